// Round 2
// 74.488 us; speedup vs baseline: 1.0299x; 1.0299x over previous
//
#include <hip/hip_runtime.h>
#include <math.h>

// (B, N, D) = (32, 128, 128)
#define BATCH 32
#define NN    128
#define BP    136     // bf16 pitch (shorts); rows 272B -> 16B aligned, bank-spread
#define NT    512     // 8 waves
#define EPS   6e-3f   // truncation: all future |prob| <= ||x||_F^2 < EPS once reached

typedef short frag8 __attribute__((ext_vector_type(8)));   // 8 bf16 = 4 VGPRs
typedef float f32x4 __attribute__((ext_vector_type(4)));   // C/D operand

__device__ __forceinline__ short bf16c(float f) {
    unsigned u = __float_as_uint(f);
    unsigned r = (u + 0x7fffu + ((u >> 16) & 1u)) >> 16;
    return (short)r;
}
__device__ __forceinline__ float bf2f(short s) {
    return __uint_as_float(((unsigned)(unsigned short)s) << 16);
}

// x_new = relu(A @ W): A row-major bf16 [128][BP], W-frags in regs.
// Writes x_new row-major into xrow AND transposed into xT; accumulates
// ||x_new||_F^2 into *ssp.  NO internal barrier: input and output buffers
// are disjoint (abuf != xrow/xT), caller barriers around the phase.
__device__ __forceinline__ void mmw(const short* __restrict__ abuf,
                                    short* __restrict__ xrow,
                                    short* __restrict__ xT,
                                    const frag8 wf[4][2],
                                    int wr, int wc, int l15, int quad,
                                    int lane, float* ssp) {
    const f32x4 z = {0.f, 0.f, 0.f, 0.f};
    f32x4 acc[4][2];
    #pragma unroll
    for (int tr = 0; tr < 4; ++tr) { acc[tr][0] = z; acc[tr][1] = z; }
    #pragma unroll
    for (int ks = 0; ks < 4; ++ks) {
        const int kb = ks * 32 + quad * 8;
        #pragma unroll
        for (int tr = 0; tr < 4; ++tr) {
            frag8 a = *(const frag8*)&abuf[(wr * 64 + tr * 16 + l15) * BP + kb];
            acc[tr][0] = __builtin_amdgcn_mfma_f32_16x16x32_bf16(a, wf[ks][0], acc[tr][0], 0, 0, 0);
            acc[tr][1] = __builtin_amdgcn_mfma_f32_16x16x32_bf16(a, wf[ks][1], acc[tr][1], 0, 0, 0);
        }
    }
    float lss = 0.f;
    #pragma unroll
    for (int tr = 0; tr < 4; ++tr)
        #pragma unroll
        for (int c2 = 0; c2 < 2; ++c2) {
            const int n  = wc * 32 + c2 * 16 + l15;      // out-feature (C col)
            const int m0 = wr * 64 + tr * 16 + quad * 4; // node (C rows, contiguous)
            f32x4 v = acc[tr][c2];
            float r0 = v[0] > 0.f ? v[0] : 0.f;
            float r1 = v[1] > 0.f ? v[1] : 0.f;
            float r2 = v[2] > 0.f ? v[2] : 0.f;
            float r3 = v[3] > 0.f ? v[3] : 0.f;
            lss = fmaf(r0, r0, lss); lss = fmaf(r1, r1, lss);
            lss = fmaf(r2, r2, lss); lss = fmaf(r3, r3, lss);
            short4 p; p.x = bf16c(r0); p.y = bf16c(r1);
            p.z = bf16c(r2); p.w = bf16c(r3);
            *(short4*)&xT[n * BP + m0] = p;              // transposed (feature-major)
            xrow[(m0 + 0) * BP + n] = p.x;               // row-major (node-major)
            xrow[(m0 + 1) * BP + n] = p.y;
            xrow[(m0 + 2) * BP + n] = p.z;
            xrow[(m0 + 3) * BP + n] = p.w;
        }
    #pragma unroll
    for (int off = 32; off >= 1; off >>= 1) lss += __shfl_down(lss, off);
    if (lane == 0) atomicAdd(ssp, lss);
}

__global__ __launch_bounds__(NT, 1)
void gcn_kernel(const float* __restrict__ xin,
                const float* __restrict__ W,
                float* __restrict__ out) {
    extern __shared__ char smem_raw[];
    short* adjb  = (short*)smem_raw;              // [128][BP] bf16 carried NORMALIZED matrix
    short* xrow  = adjb + NN * BP;                // [128][BP] bf16 x row-major
    short* xT    = xrow + NN * BP;                // [128][BP] WT stage, then x transposed
    short* ybuf2 = xT + NN * BP;                  // [128][BP] xin stage, then y = adjn@x
    float* prob  = (float*)(ybuf2 + NN * BP);     // [128] masked probs (fp32)
    float* dinv  = prob + NN;                     // [128]
    float* rs    = dinv + NN;                     // [128] rowsums of carried normalized matrix
    __shared__ float sumsq;                       // ||x||_F^2
    __shared__ float wnorm;                       // ||W||_F^2
    __shared__ float sprob;                       // sum_{j<i} prob[j]
    __shared__ float aii;                         // adjb[i][i] before step-i writes

    const int t = threadIdx.x;
    const int b = blockIdx.x;
    const int lane = t & 63, w = t >> 6;          // 8 waves
    const int wr = w >> 2, wc = w & 3;            // E/F wave tile: rows 64*wr, cols 32*wc
    const int l15 = lane & 15, quad = lane >> 4;

    const float* xin_b = xin + (size_t)b * NN * NN;
    float*       out_b = out + (size_t)b * NN * NN;

    if (t == 0) { sumsq = 0.0f; wnorm = 0.0f; sprob = 0.0f; }
    __syncthreads();   // order the zero-init before any atomicAdd below

    // ---- stage: adjb=0, xin->ybuf2 row-major bf16, W->xT transposed bf16 + wnorm
    for (int v = t; v < NN * BP / 2; v += NT) ((int*)adjb)[v] = 0;
    for (int v = t; v < NN * NN / 4; v += NT) {
        float4 f = ((const float4*)xin_b)[v];
        const int node = v >> 5, c = (v & 31) * 4;
        short4 p; p.x = bf16c(f.x); p.y = bf16c(f.y); p.z = bf16c(f.z); p.w = bf16c(f.w);
        *(short4*)&ybuf2[node * BP + c] = p;
    }
    {
        float lw = 0.0f;
        #pragma unroll
        for (int k = 0; k < 8; ++k) {
            const int idx = k * NT + t;           // float4 index into W
            float4 f = ((const float4*)W)[idx];
            lw = fmaf(f.x, f.x, lw); lw = fmaf(f.y, f.y, lw);
            lw = fmaf(f.z, f.z, lw); lw = fmaf(f.w, f.w, lw);
            const int e0 = idx * 4;
            const int d = e0 >> 7, e = e0 & 127;  // W[d][e..e+3]
            xT[(e + 0) * BP + d] = bf16c(f.x);    // WT[e][d]
            xT[(e + 1) * BP + d] = bf16c(f.y);
            xT[(e + 2) * BP + d] = bf16c(f.z);
            xT[(e + 3) * BP + d] = bf16c(f.w);
        }
        #pragma unroll
        for (int off = 32; off >= 1; off >>= 1) lw += __shfl_down(lw, off);
        if (lane == 0) atomicAdd(&wnorm, lw);
    }
    __syncthreads();

    // ---- wfrag: B[k=d][n=e] = W[d][e], read contiguous from staged WT
    frag8 wfrag[4][2];
    #pragma unroll
    for (int ks = 0; ks < 4; ++ks)
        #pragma unroll
        for (int c2 = 0; c2 < 2; ++c2) {
            const int e  = wc * 32 + c2 * 16 + l15;
            const int kb = ks * 32 + quad * 8;
            wfrag[ks][c2] = *(const frag8*)&xT[e * BP + kb];
        }
    if (t < NN) {
        adjb[t * BP + t] = (short)0x3F80;   // bf16 1.0
        out_b[t * NN + t] = 1.0f;
        rs[t] = 1.0f;                       // rowsum of normalized I
    }
    const bool wok = (wnorm <= 1.0f);       // ||W||_2 <= ||W||_F <= 1
    __syncthreads();                        // wfrag reads done before mmw writes xT

    // ---- x0 = relu(xin @ W) -> xrow + xT + sumsq   (reads ybuf2: no inner barrier)
    mmw(ybuf2, xrow, xT, wfrag, wr, wc, l15, quad, lane, &sumsq);
    __syncthreads();
    float ss = sumsq;
    bool skip = (ss == 0.0f) || (wok && ss < EPS);

    // ---- scan i = 1..127
    for (int i = 1; i < NN; ++i) {
        if (skip) {
            const int i0 = i;
            const int nrow = NN - i0;
            for (int v = t; v < nrow * (NN / 4); v += NT) {
                const int r = i0 + (v >> 5), c = (v & 31) * 4;
                float4 zz = {0.f, 0.f, 0.f, 0.f};
                *(float4*)&out_b[r * NN + c] = zz;
            }
            for (int v = t; v < i0 * nrow; v += NT) {
                const int r = v / nrow, c = i0 + v % nrow;
                out_b[r * NN + c] = 0.f;
            }
            __syncthreads();
            if (t >= i0 && t < NN) out_b[t * NN + t] = 1.0f;
            break;
        }

        // --- P: prob via MFMA broadcast. Wave w owns rows w*16..w*16+15.
        //     B cols all equal x_i -> every lane holds prob replicated.
        {
            if (t == 0) aii = bf2f(adjb[i * BP + i]);  // [i][i] untouched by this phase
            const f32x4 z = {0.f, 0.f, 0.f, 0.f};
            f32x4 pa = z, pb = z;
            #pragma unroll
            for (int ks = 0; ks < 4; ++ks) {
                const int kb = ks * 32 + quad * 8;
                frag8 a  = *(const frag8*)&xrow[(w * 16 + l15) * BP + kb];
                frag8 bb = *(const frag8*)&xrow[i * BP + kb];   // broadcast read
                if (ks & 1) pb = __builtin_amdgcn_mfma_f32_16x16x32_bf16(a, bb, pb, 0, 0, 0);
                else        pa = __builtin_amdgcn_mfma_f32_16x16x32_bf16(a, bb, pa, 0, 0, 0);
            }
            f32x4 pc = pa + pb;
            float sp = 0.f;
            if (l15 == 0) {                        // lanes 0,16,32,48: 4 probs each
                #pragma unroll
                for (int r = 0; r < 4; ++r) {
                    const int j = w * 16 + quad * 4 + r;
                    const float p = pc[r];
                    const bool m = (j < i);
                    prob[j] = m ? p : 0.f;
                    if (m) {
                        const short pb16 = bf16c(p);
                        adjb[i * BP + j] = pb16;  adjb[j * BP + i] = pb16;
                        out_b[i * NN + j] = p;    out_b[j * NN + i] = p;
                        sp += p;
                    }
                }
            }
            sp += __shfl_down(sp, 32);             // lanes 0+=32, 16+=48
            sp += __shfl_down(sp, 16);             // lane 0 += lane 16
            if (lane == 0) atomicAdd(&sprob, sp);
        }
        __syncthreads();

        // --- Q: dinv from incremental degrees (col/row i were 0 off-diag pre-step)
        if (t < NN) {
            const float d = (t == i) ? (aii + sprob) : (rs[t] + prob[t]);
            dinv[t] = 1.0f / sqrtf(d);
        }
        if (t == NN) sumsq = 0.f;                  // reset for this step's F
        __syncthreads();

        // --- D: normalize carried bf16 matrix in place + new rowsums
        {
            const int r = t >> 2, q = t & 3;
            const float dr = dinv[r];
            float lrs = 0.f;
            #pragma unroll
            for (int g = 0; g < 4; ++g) {
                const int c = q * 32 + g * 8;
                frag8 v = *(const frag8*)&adjb[r * BP + c];
                float dc[8];
                *(float4*)&dc[0] = *(const float4*)&dinv[c];
                *(float4*)&dc[4] = *(const float4*)&dinv[c + 4];
                frag8 o;
                #pragma unroll
                for (int k = 0; k < 8; ++k) {
                    const float f = bf2f(v[k]) * dr * dc[k];
                    lrs += f;
                    o[k] = bf16c(f);
                }
                *(frag8*)&adjb[r * BP + c] = o;
            }
            lrs += __shfl_down(lrs, 2, 4);
            lrs += __shfl_down(lrs, 1, 4);
            if (q == 0) rs[r] = lrs;
            if (t == NT - 1) sprob = 0.f;          // safe: Q's reads are behind a barrier
        }
        __syncthreads();

        // --- E: y = adjn @ x  (A: adjb rows; B: x cols via xT rows; both b128)
        //     writes into dead ybuf2 -> no pre-write drain barrier needed
        {
            const f32x4 z = {0.f, 0.f, 0.f, 0.f};
            f32x4 acc[4][2];
            #pragma unroll
            for (int tr = 0; tr < 4; ++tr) { acc[tr][0] = z; acc[tr][1] = z; }
            #pragma unroll
            for (int ks = 0; ks < 4; ++ks) {
                const int kb = ks * 32 + quad * 8;
                frag8 b0 = *(const frag8*)&xT[(wc * 32 + l15) * BP + kb];
                frag8 b1 = *(const frag8*)&xT[(wc * 32 + 16 + l15) * BP + kb];
                #pragma unroll
                for (int tr = 0; tr < 4; ++tr) {
                    frag8 a = *(const frag8*)&adjb[(wr * 64 + tr * 16 + l15) * BP + kb];
                    acc[tr][0] = __builtin_amdgcn_mfma_f32_16x16x32_bf16(a, b0, acc[tr][0], 0, 0, 0);
                    acc[tr][1] = __builtin_amdgcn_mfma_f32_16x16x32_bf16(a, b1, acc[tr][1], 0, 0, 0);
                }
            }
            #pragma unroll
            for (int tr = 0; tr < 4; ++tr)
                #pragma unroll
                for (int c2 = 0; c2 < 2; ++c2) {
                    const int n  = wc * 32 + c2 * 16 + l15;      // feature (C col)
                    const int m0 = wr * 64 + tr * 16 + quad * 4; // node (C rows)
                    f32x4 v = acc[tr][c2];
                    ybuf2[(m0 + 0) * BP + n] = bf16c(v[0]);      // y row-major [node][d]
                    ybuf2[(m0 + 1) * BP + n] = bf16c(v[1]);
                    ybuf2[(m0 + 2) * BP + n] = bf16c(v[2]);
                    ybuf2[(m0 + 3) * BP + n] = bf16c(v[3]);
                }
        }
        __syncthreads();

        // --- F: x = relu(y @ W) -> xrow + xT + sumsq  (no inner barrier)
        mmw(ybuf2, xrow, xT, wfrag, wr, wc, l15, quad, lane, &sumsq);
        __syncthreads();
        ss = sumsq;
        skip = (ss == 0.0f) || (wok && ss < EPS);
    }
}

extern "C" void kernel_launch(void* const* d_in, const int* in_sizes, int n_in,
                              void* d_out, int out_size, void* d_ws, size_t ws_size,
                              hipStream_t stream) {
    const float* x = (const float*)d_in[0];   // (32,128,128) fp32
    const float* W = (const float*)d_in[1];   // (128,128) fp32
    float* out = (float*)d_out;               // (32,128,128) fp32

    const size_t shmem = (size_t)4 * NN * BP * sizeof(short)
                       + (size_t)3 * NN * sizeof(float);   // 140,800 B
    hipFuncSetAttribute((const void*)gcn_kernel,
                        hipFuncAttributeMaxDynamicSharedMemorySize, (int)shmem);

    gcn_kernel<<<dim3(BATCH), dim3(NT), shmem, stream>>>(x, W, out);
}